// Round 1
// baseline (353.297 us; speedup 1.0000x reference)
//
#include <hip/hip_runtime.h>
#include <cstdint>
#include <cstddef>

// Problem constants
#define NB   32    // query batch
#define NSUP 25    // support images
#define KCLS 5     // classes
#define NC   512   // input channels
#define ND   128   // dk = dv
#define NP   196   // h*w
#define JS   208   // per-support padded col count (13*16)
#define CLS_COLS 1040  // 5*208 padded per-class col domain
#define NT1  65        // 16-col tiles in pass 1 (1040/16)
#define NIT2 33        // 32-col chunks in pass 2 (covers 1056, last 16 padded)

typedef __attribute__((ext_vector_type(8))) short short8;   // 8 x bf16 (4 VGPRs)
typedef __attribute__((ext_vector_type(4))) float floatx4;  // MFMA C/D

__device__ inline short f2bf(float x) {
  union { float f; uint32_t u; } v; v.f = x;
  uint32_t r = (v.u + 0x7FFFu + ((v.u >> 16) & 1u)) >> 16;  // RNE
  return (short)(r & 0xFFFFu);
}

// ---------------------------------------------------------------------------
// Kernel 1: 1x1-conv projections (fp32 compute).
//   Writes (bf16): Qt[b][p][d]  (d-contiguous, for MFMA A-frags)
//                  Kt[n][j:208][d] (d-contiguous, rows 196..207 left as poison)
//                  Vt[n][d][j:208] (j-contiguous, cols 196..207 poison)
//   Writes (fp32): outVq[b][d][p] directly into d_out (query_v_flat).
// grid = 2 mats * 57 imgs * 4 dtiles(32) = 456 blocks, 256 threads (p = tid)
// ---------------------------------------------------------------------------
__global__ __launch_bounds__(256) void proj_kernel(
    const float* __restrict__ supp, const float* __restrict__ qry,
    const float* __restrict__ Wqk, const float* __restrict__ Wv,
    uint16_t* __restrict__ Qt, uint16_t* __restrict__ Kt,
    uint16_t* __restrict__ Vt, float* __restrict__ outVq)
{
  const int bx  = blockIdx.x;
  const int mat = bx / 228;          // 0 = W_qk, 1 = W_v
  const int rem = bx % 228;
  const int img = rem >> 2;          // 0..56  (0..31 query, 32..56 support)
  const int d0  = (rem & 3) * 32;

  const float* __restrict__ W = mat ? Wv : Wqk;
  const float* __restrict__ X = (img < NB)
      ? (qry  + (size_t)img * NC * NP)
      : (supp + (size_t)(img - NB) * NC * NP);

  const int p  = (int)threadIdx.x;
  const int pe = p < NP ? p : NP - 1;  // clamp to stay in-bounds

  float acc[32];
  #pragma unroll
  for (int i = 0; i < 32; ++i) acc[i] = 0.f;

  #pragma unroll 4
  for (int c = 0; c < NC; ++c) {
    const float x = X[c * NP + pe];            // coalesced vector load
    #pragma unroll
    for (int dd = 0; dd < 32; ++dd)            // W index wave-uniform -> s_load
      acc[dd] = fmaf(W[(d0 + dd) * NC + c], x, acc[dd]);
  }

  if (p >= NP) return;

  if (mat == 0) {
    if (img < NB) {
      uint16_t* dst = Qt + ((size_t)(img * NP + p)) * ND + d0;
      #pragma unroll
      for (int dd = 0; dd < 32; ++dd) dst[dd] = (uint16_t)f2bf(acc[dd]);
    } else {
      const int n = img - NB;
      uint16_t* dst = Kt + ((size_t)(n * JS + p)) * ND + d0;
      #pragma unroll
      for (int dd = 0; dd < 32; ++dd) dst[dd] = (uint16_t)f2bf(acc[dd]);
    }
  } else {
    if (img < NB) {
      #pragma unroll
      for (int dd = 0; dd < 32; ++dd)
        outVq[((size_t)(img * ND + d0 + dd)) * NP + p] = acc[dd];  // fp32 exact-ish
    } else {
      const int n = img - NB;
      #pragma unroll
      for (int dd = 0; dd < 32; ++dd)
        Vt[((size_t)(n * ND + d0 + dd)) * JS + p] = (uint16_t)f2bf(acc[dd]);
    }
  }
}

// ---------------------------------------------------------------------------
// Kernel 2: per-class masked attention, bf16 MFMA 16x16x32, two-pass flash.
// One wave per (b, class, 32-row p-tile): grid = 32*5*7 = 1120 blocks x 64 thr.
// Pass 1: QK -> per-row max M (per-lane running max, shuffle-merge once).
// Pass 2: recompute QK per 32-col chunk, e = exp(l - M) (unnormalized),
//         D-layout -> LDS chunk -> A-layout, PV accumulates; O /= S at end.
// Verified layouts (guide §3): A[m=lane&15][k=(lane>>4)*8+j],
//                              B[n=lane&15][k=(lane>>4)*8+j],
//                              D col=lane&15, row=(lane>>4)*4+reg.
// ---------------------------------------------------------------------------
__global__ __launch_bounds__(64) void attn_kernel(
    const uint16_t* __restrict__ Qt, const uint16_t* __restrict__ Kt,
    const uint16_t* __restrict__ Vt, const int* __restrict__ labels,
    float* __restrict__ out)
{
  __shared__ float chunk[32 * 36];  // pitch 36 floats: 16B-aligned rows, 2-way-max banks
  __shared__ int cls[8];

  const int bx  = blockIdx.x;
  const int b   = bx / 35;
  const int rem = bx % 35;
  const int kc  = rem / 7;
  const int pt  = rem % 7;
  const int p0  = pt * 32;

  const int lane = (int)threadIdx.x;  // 0..63
  const int ln   = lane & 15;
  const int q    = lane >> 4;

  if (lane == 0) {
    int m = 0;
    #pragma unroll
    for (int i = 0; i < 8; ++i) cls[i] = 0;
    for (int n = 0; n < NSUP; ++n)
      if (labels[n] == kc && m < 5) cls[m++] = n;
  }
  __syncthreads();

  // --- Q A-fragments, resident for whole kernel (2 m-tiles x 4 k-steps) ---
  short8 aq[2][4];
  #pragma unroll
  for (int mt = 0; mt < 2; ++mt) {
    int p = p0 + mt * 16 + ln;
    if (p > NP - 1) p = NP - 1;  // duplicate last row for pad rows (keeps finite)
    const uint16_t* base = Qt + ((size_t)(b * NP + p)) * ND + q * 8;
    #pragma unroll
    for (int ks = 0; ks < 4; ++ks)
      aq[mt][ks] = *(const short8*)(base + ks * 32);
  }

  // --- Pass 1: row maxima ---
  float vmax[2][4];
  #pragma unroll
  for (int mt = 0; mt < 2; ++mt)
    #pragma unroll
    for (int r = 0; r < 4; ++r) vmax[mt][r] = -1e30f;

  for (int jt = 0; jt < NT1; ++jt) {
    const int col = jt * 16 + ln;       // < 1040
    const int s   = col / JS;
    const int j   = col - s * JS;       // 0..207
    const int n   = cls[s];
    const bool valid = (j < NP);        // mask per-support pad cols
    const uint16_t* kb = Kt + ((size_t)(n * JS + j)) * ND + q * 8;
    short8 bk[4];
    #pragma unroll
    for (int ks = 0; ks < 4; ++ks) bk[ks] = *(const short8*)(kb + ks * 32);
    #pragma unroll
    for (int mt = 0; mt < 2; ++mt) {
      floatx4 d = {0.f, 0.f, 0.f, 0.f};
      #pragma unroll
      for (int ks = 0; ks < 4; ++ks)
        d = __builtin_amdgcn_mfma_f32_16x16x32_bf16(aq[mt][ks], bk[ks], d, 0, 0, 0);
      #pragma unroll
      for (int r = 0; r < 4; ++r) {
        const float l = valid ? d[r] : -1e30f;
        vmax[mt][r] = fmaxf(vmax[mt][r], l);
      }
    }
  }

  float M[2][4], Ssum[2][4];
  #pragma unroll
  for (int mt = 0; mt < 2; ++mt)
    #pragma unroll
    for (int r = 0; r < 4; ++r) {
      float m = vmax[mt][r];                    // reduce over 16 lanes of same quad
      m = fmaxf(m, __shfl_xor(m, 1));
      m = fmaxf(m, __shfl_xor(m, 2));
      m = fmaxf(m, __shfl_xor(m, 4));
      m = fmaxf(m, __shfl_xor(m, 8));
      M[mt][r] = m;
      Ssum[mt][r] = 0.f;
    }

  // --- Pass 2: weights + PV (unnormalized) ---
  floatx4 acc[8][2];
  #pragma unroll
  for (int dt = 0; dt < 8; ++dt)
    #pragma unroll
    for (int mt = 0; mt < 2; ++mt)
      acc[dt][mt] = (floatx4){0.f, 0.f, 0.f, 0.f};

  for (int it = 0; it < NIT2; ++it) {
    #pragma unroll
    for (int t = 0; t < 2; ++t) {
      const int jt  = it * 2 + t;
      const int col = jt * 16 + ln;        // up to 1055 (tile 65 is pad)
      int s = col / JS; if (s > 4) s = 4;  // protect cls[] for pad tile
      int j = col - s * JS; if (j > JS - 1) j = JS - 1;
      const int n = cls[s];
      const bool valid = (j < NP) && (col < CLS_COLS);
      const uint16_t* kb = Kt + ((size_t)(n * JS + j)) * ND + q * 8;
      short8 bk[4];
      #pragma unroll
      for (int ks = 0; ks < 4; ++ks) bk[ks] = *(const short8*)(kb + ks * 32);
      #pragma unroll
      for (int mt = 0; mt < 2; ++mt) {
        floatx4 d = {0.f, 0.f, 0.f, 0.f};
        #pragma unroll
        for (int ks = 0; ks < 4; ++ks)
          d = __builtin_amdgcn_mfma_f32_16x16x32_bf16(aq[mt][ks], bk[ks], d, 0, 0, 0);
        #pragma unroll
        for (int r = 0; r < 4; ++r) {
          const float ev = valid ? __expf(d[r] - M[mt][r]) : 0.f;  // <= 1
          Ssum[mt][r] += ev;
          chunk[(mt * 16 + q * 4 + r) * 36 + t * 16 + ln] = ev;    // D-layout write
        }
      }
    }
    __syncthreads();

    // A-layout reads of the weight chunk (fp32 -> bf16)
    short8 a2[2];
    #pragma unroll
    for (int mt = 0; mt < 2; ++mt) {
      const float* src = &chunk[(mt * 16 + ln) * 36 + q * 8];
      short8 a;
      #pragma unroll
      for (int x = 0; x < 8; ++x) a[x] = f2bf(src[x]);
      a2[mt] = a;
    }

    // V B-fragments: k = jj (8 contiguous j within one support), n = d
    const int jjg = it * 32 + q * 8;
    int s2 = jjg / JS; if (s2 > 4) s2 = 4;
    int j2 = jjg - s2 * JS; if (j2 > 200) j2 = 200;  // pad region: weights are 0
    const int n2 = cls[s2];
    #pragma unroll
    for (int dt = 0; dt < 8; ++dt) {
      const uint16_t* vb = Vt + ((size_t)(n2 * ND + dt * 16 + ln)) * JS + j2;
      const short8 bv = *(const short8*)vb;
      #pragma unroll
      for (int mt = 0; mt < 2; ++mt)
        acc[dt][mt] = __builtin_amdgcn_mfma_f32_16x16x32_bf16(a2[mt], bv, acc[dt][mt], 0, 0, 0);
    }
    __syncthreads();  // chunk reuse next iteration
  }

  // --- Normalize by row sums and store prototypes[b][k][d][p] ---
  float invS[2][4];
  #pragma unroll
  for (int mt = 0; mt < 2; ++mt)
    #pragma unroll
    for (int r = 0; r < 4; ++r) {
      float sv = Ssum[mt][r];
      sv += __shfl_xor(sv, 1);
      sv += __shfl_xor(sv, 2);
      sv += __shfl_xor(sv, 4);
      sv += __shfl_xor(sv, 8);
      invS[mt][r] = 1.f / sv;   // sv >= 1 (max element contributes exp(0)=1)
    }

  #pragma unroll
  for (int dt = 0; dt < 8; ++dt) {
    const int d = dt * 16 + ln;
    #pragma unroll
    for (int mt = 0; mt < 2; ++mt) {
      const int prow = p0 + mt * 16 + q * 4;  // rows q*4..q*4+3 (contiguous)
      if (prow < NP) {                        // full float4 or none (196 % 4 == 0)
        floatx4 v;
        #pragma unroll
        for (int r = 0; r < 4; ++r) v[r] = acc[dt][mt][r] * invS[mt][r];
        *(floatx4*)(out + ((size_t)((b * KCLS + kc) * ND + d)) * NP + prow) = v;
      }
    }
  }
}

// ---------------------------------------------------------------------------
extern "C" void kernel_launch(void* const* d_in, const int* in_sizes, int n_in,
                              void* d_out, int out_size, void* d_ws, size_t ws_size,
                              hipStream_t stream) {
  const float* supp   = (const float*)d_in[0];  // [25,512,14,14]
  const float* qry    = (const float*)d_in[1];  // [32,512,14,14]
  const int*   labels = (const int*)d_in[2];    // [25]
  const float* Wqk    = (const float*)d_in[3];  // [128,512]
  const float* Wv     = (const float*)d_in[4];  // [128,512]
  float* out = (float*)d_out;

  // ws layout (bf16 as uint16): Qt | Kt | Vt  (~4.27 MB total)
  uint16_t* Qt = (uint16_t*)d_ws;
  uint16_t* Kt = Qt + (size_t)NB * NP * ND;     // 32*196*128
  uint16_t* Vt = Kt + (size_t)NSUP * JS * ND;   // 25*208*128
  float* outVq = out + (size_t)NB * KCLS * ND * NP;  // query_v_flat region

  proj_kernel<<<456, 256, 0, stream>>>(supp, qry, Wqk, Wv, Qt, Kt, Vt, outVq);
  attn_kernel<<<1120, 64, 0, stream>>>(Qt, Kt, Vt, labels, out);
}